// Round 7
// baseline (631.183 us; speedup 1.0000x reference)
//
#include <hip/hip_runtime.h>
#include <hip/hip_bf16.h>
#include <cstdint>
#include <cstddef>

#define N_NODES 100000
#define DIM 512
#define NE 200000
#define NSB 196    // ceil(N_NODES/512)

typedef __attribute__((ext_vector_type(4))) float floatx4;
typedef __attribute__((ext_vector_type(8))) short shortx8;

__device__ __forceinline__ unsigned short f2bf(float f) {
    union { float f; uint32_t u; } v; v.f = f;
    uint32_t r = v.u + 0x7fff + ((v.u >> 16) & 1);   // RNE
    return (unsigned short)(r >> 16);
}

__device__ __forceinline__ float bf2f(unsigned short h) {
    union { uint32_t u; float f; } v; v.u = ((uint32_t)h) << 16;
    return v.f;
}

// 8x fp32 -> 8x bf16 (RNE) via packed v_cvt_pk_bf16_f32
__device__ __forceinline__ shortx8 cvt8(const float4 a, const float4 b) {
    union { __hip_bfloat162 h2[4]; shortx8 s8; } u;
    u.h2[0] = __float22bfloat162_rn(make_float2(a.x, a.y));
    u.h2[1] = __float22bfloat162_rn(make_float2(a.z, a.w));
    u.h2[2] = __float22bfloat162_rn(make_float2(b.x, b.y));
    u.h2[3] = __float22bfloat162_rn(make_float2(b.z, b.w));
    return u.s8;
}

// ---------------- per-etype in-degree counts + Wc = (W0+W1+W2)/3 (fused, independent) ----
__global__ __launch_bounds__(256) void count_combine_kernel(
    const int* __restrict__ d0, const int* __restrict__ d1,
    const int* __restrict__ d2, int* __restrict__ cnt,
    const float* __restrict__ W0, const float* __restrict__ W1,
    const float* __restrict__ W2, unsigned short* __restrict__ Wc) {
    int t = blockIdx.x * 256 + threadIdx.x;
    if (t < DIM * DIM)
        Wc[t] = f2bf((W0[t] + W1[t] + W2[t]) * (1.0f / 3.0f));
    if (t < 3 * NE) {
        int e = t / NE;
        int i = t - e * NE;
        const int* dp = (e == 0) ? d0 : (e == 1) ? d1 : d2;
        atomicAdd(&cnt[e * N_NODES + dp[i]], 1);
    }
}

// ---------------- scan pass 1: per-block (512 rows) sums of total row length ----------------
__global__ __launch_bounds__(512) void scan1_kernel(
    const int* __restrict__ cnt, int* __restrict__ bsum) {
    int t = threadIdx.x;
    int n = blockIdx.x * 512 + t;
    int rl = 0;
    if (n < N_NODES) rl = cnt[n] + cnt[N_NODES + n] + cnt[2 * N_NODES + n];
    int v = rl;
    #pragma unroll
    for (int off = 32; off > 0; off >>= 1) v += __shfl_xor(v, off);
    __shared__ int ws_[8];
    if ((t & 63) == 0) ws_[t >> 6] = v;
    __syncthreads();
    if (t == 0) {
        int s = 0;
        #pragma unroll
        for (int i = 0; i < 8; ++i) s += ws_[i];
        bsum[blockIdx.x] = s;
    }
}

// ---------------- scan pass 2+3 fused: each block scans the 196 block sums in LDS,
// then scans its own 512 row lengths -> row_start + cursor ----------------
__global__ __launch_bounds__(512) void scan3_kernel(
    const int* __restrict__ cnt, const int* __restrict__ bsum,
    int* __restrict__ row_start, int* __restrict__ cursor) {
    __shared__ int shb[512];
    __shared__ int sh[512];
    int t = threadIdx.x;
    shb[t] = (t < NSB) ? bsum[t] : 0;
    __syncthreads();
    #pragma unroll
    for (int off = 1; off < 512; off <<= 1) {
        int add = (t >= off) ? shb[t - off] : 0;
        __syncthreads();
        shb[t] += add;
        __syncthreads();
    }
    int n = blockIdx.x * 512 + t;
    int rl = 0;
    if (n < N_NODES) rl = cnt[n] + cnt[N_NODES + n] + cnt[2 * N_NODES + n];
    sh[t] = rl;
    __syncthreads();
    #pragma unroll
    for (int off = 1; off < 512; off <<= 1) {
        int add = (t >= off) ? sh[t - off] : 0;
        __syncthreads();
        sh[t] += add;
        __syncthreads();
    }
    if (n < N_NODES) {
        int bexcl = shb[blockIdx.x] - bsum[blockIdx.x];   // exclusive block prefix
        int excl = sh[t] - rl + bexcl;
        row_start[n] = excl;
        cursor[n] = excl;
    }
}

// ---------------- bin edges into CSR: src tagged with etype in bits 30-31 ----------------
__global__ __launch_bounds__(256) void bin_kernel(
    const int* __restrict__ s0, const int* __restrict__ d0,
    const int* __restrict__ s1, const int* __restrict__ d1,
    const int* __restrict__ s2, const int* __restrict__ d2,
    int* __restrict__ cursor, int* __restrict__ src_tag) {
    int t = blockIdx.x * 256 + threadIdx.x;
    if (t >= 3 * NE) return;
    int e = t / NE;
    int i = t - e * NE;
    const int* sp; const int* dp;
    if (e == 0)      { sp = s0; dp = d0; }
    else if (e == 1) { sp = s1; dp = d1; }
    else             { sp = s2; dp = d2; }
    int d = dp[i];
    int pos = atomicAdd(&cursor[d], 1);
    src_tag[pos] = sp[i] | (e << 30);
}

// ---------------- GEMM: H = bf16(X) @ Wc^T, A-only LDS + B direct from L2 ----------------
// Round-4 geometry (128x128 tile, 256 threads = 2x2 waves, 4x4 16x16x32 frags, BK=64,
// 8 K-steps) -- the best measured structure (123.6us) -- with the diagnosed stall
// removed at ZERO occupancy cost: B (0.5 MB, L2-resident) skips LDS entirely. Each
// thread loads its 8 B-fragments (16B each) per step straight from global with
// compile-time immediate offsets off 4 row base pointers; the wave's pattern is
// 16 rows x 64B, every 64B line fully consumed -> perfectly coalesced, L2-served.
// A keeps the verified reg-stage path (fp32 -> cvt_pk -> swizzled ds_write) into a
// 2 x 16 KB double-buffer, one tile ahead. The single per-step barrier now drains
// essentially only lgkm (A ds_writes) -- the 16-deep global_load_lds vmcnt(0) drain
// that throttled rounds 4-6 is gone. LDS 32 KB, ~3 blocks/CU -> inter-block overlap
// (the thing rounds 5/6 destroyed) is preserved.
// Swizzle (round-4 verified): A octet c stored at c^(row&7) within 128B rows.
// XCD-bijective swizzle: 3128 = 8*391 blocks; 4 N-tile siblings share one XCD's L2.
__global__ __launch_bounds__(256) void gemm_kernel(
    const float* __restrict__ X, const unsigned short* __restrict__ B,
    unsigned short* __restrict__ H, int M) {
    __shared__ alignas(16) unsigned short As[2][128 * 64];   // 2 x 16 KB
    const int tid = threadIdx.x;
    const int lane = tid & 63;
    const int w = tid >> 6;            // 0..3
    const int wr = w >> 1, wc = w & 1; // wave grid 2x2
    const int q = lane >> 4, r = lane & 15;

    int lid = ((int)blockIdx.x & 7) * 391 + ((int)blockIdx.x >> 3);
    int mt = lid >> 2, nt = lid & 3;
    int m0 = mt * 128, n0 = nt * 128;

    // A staging geometry: chunk ca = i*256 + tid; row = i*32 + (tid>>3), octet = tid&7
    const int arow = tid >> 3;          // 0..31
    const int ac = tid & 7;             // k-octet
    const int acs = ac ^ (arow & 7);    // swizzled octet position
    const unsigned abyte = (unsigned)arow * 128 + (unsigned)acs * 16;
    const float* aptr[4];
    #pragma unroll
    for (int i = 0; i < 4; ++i) {
        int gm = m0 + i * 32 + arow; if (gm >= M) gm = M - 1;   // clamp tail reads
        aptr[i] = X + (size_t)gm * DIM + ac * 8;
    }
    float4 areg[4][2];
    auto aload = [&](int k0_) {
        #pragma unroll
        for (int i = 0; i < 4; ++i) {
            areg[i][0] = *(const float4*)(aptr[i] + k0_);
            areg[i][1] = *(const float4*)(aptr[i] + k0_ + 4);
        }
    };
    auto writeA = [&](int buf) {
        #pragma unroll
        for (int i = 0; i < 4; ++i)
            *(shortx8*)((char*)As[buf] + i * 4096 + abyte) =
                cvt8(areg[i][0], areg[i][1]);
    };

    // B fragment row base pointers (per-lane; rows are output cols of H)
    const unsigned short* bptr[4];
    #pragma unroll
    for (int nj = 0; nj < 4; ++nj)
        bptr[nj] = B + (size_t)(n0 + wc * 64 + nj * 16 + r) * DIM;

    floatx4 acc[4][4] = {};

    // prologue: tile0 -> LDS buf0; tile1 -> regs
    aload(0);
    writeA(0);
    aload(64);
    __syncthreads();

    #pragma unroll
    for (int t = 0; t < 8; ++t) {
        const int cur = t & 1;
        if (t < 7) writeA(cur ^ 1);        // A tile t+1 (regs loaded last iter)
        if (t < 6) aload((t + 2) * 64);    // A tile t+2 -> regs (ages over this step)
        // B fragments for this step: 8 x 16B, immediate offsets, L2-resident
        shortx8 bf[2][4];
        #pragma unroll
        for (int kk = 0; kk < 2; ++kk)
            #pragma unroll
            for (int nj = 0; nj < 4; ++nj)
                bf[kk][nj] = *(const shortx8*)(bptr[nj] + t * 64 + (kk * 4 + q) * 8);
        #pragma unroll
        for (int kk = 0; kk < 2; ++kk) {
            const int sc = ((kk * 4 + q) ^ (r & 7)) * 16;   // swizzled byte-in-row
            shortx8 af[4];
            #pragma unroll
            for (int mi = 0; mi < 4; ++mi)
                af[mi] = *(const shortx8*)((const char*)As[cur] +
                         (wr * 64 + mi * 16 + r) * 128 + sc);
            #pragma unroll
            for (int mi = 0; mi < 4; ++mi)
                #pragma unroll
                for (int nj = 0; nj < 4; ++nj)
                    acc[mi][nj] = __builtin_amdgcn_mfma_f32_16x16x32_bf16(
                        af[mi], bf[kk][nj], acc[mi][nj], 0, 0, 0);
        }
        __syncthreads();   // next step overwrites As[cur]; drain is lgkm + aged areg
    }

    // C/D layout: col = r, row = q*4 + rg within each 16x16 frag
    #pragma unroll
    for (int mi = 0; mi < 4; ++mi) {
        #pragma unroll
        for (int rg = 0; rg < 4; ++rg) {
            int gm = m0 + wr * 64 + mi * 16 + q * 4 + rg;
            if (gm < M) {
                #pragma unroll
                for (int nj = 0; nj < 4; ++nj)
                    H[(size_t)gm * DIM + n0 + wc * 64 + nj * 16 + r] =
                        f2bf(acc[mi][nj][rg]);
            }
        }
    }
}

// ---------------- fused gather + ReLU + LayerNorm ----------------
// One wave per node; wave holds the full 512-dim row (lane*8..lane*8+8) in registers.
// Cooperative tag load (64/batch) + 4-wide unrolled edge loop for memory-level parallelism.
__global__ __launch_bounds__(256) void gather_ln_kernel(
    const unsigned short* __restrict__ h, const int* __restrict__ row_start,
    const int* __restrict__ cnt, const int* __restrict__ src_tag,
    const float* __restrict__ gamma, const float* __restrict__ beta,
    float* __restrict__ out) {
    const int lane = threadIdx.x & 63;
    const int n = blockIdx.x * 4 + (threadIdx.x >> 6);
    if (n >= N_NODES) return;
    const int c0 = cnt[n], c1 = cnt[N_NODES + n], c2 = cnt[2 * N_NODES + n];
    const int len = c0 + c1 + c2;
    const float w0 = 1.0f / (3.0f * (float)max(c0, 1));
    const float w1 = 1.0f / (3.0f * (float)max(c1, 1));
    const float w2 = 1.0f / (3.0f * (float)max(c2, 1));
    const int beg = row_start[n];
    const size_t lx = (size_t)lane * 8;
    float acc[8] = {};
    for (int base = 0; base < len; base += 64) {
        int rem = len - base;
        int m = rem < 64 ? rem : 64;
        int tag = (lane < m) ? src_tag[beg + base + lane] : 0;
        int j = 0;
        for (; j + 4 <= m; j += 4) {
            int u0 = __shfl(tag, j),     u1 = __shfl(tag, j + 1);
            int u2 = __shfl(tag, j + 2), u3 = __shfl(tag, j + 3);
            int e0 = ((unsigned)u0) >> 30, e1 = ((unsigned)u1) >> 30;
            int e2 = ((unsigned)u2) >> 30, e3 = ((unsigned)u3) >> 30;
            float g0 = (e0 == 0) ? w0 : ((e0 == 1) ? w1 : w2);
            float g1 = (e1 == 0) ? w0 : ((e1 == 1) ? w1 : w2);
            float g2 = (e2 == 0) ? w0 : ((e2 == 1) ? w1 : w2);
            float g3 = (e3 == 0) ? w0 : ((e3 == 1) ? w1 : w2);
            shortx8 v0 = *(const shortx8*)(h + (size_t)(u0 & 0x3FFFFFFF) * DIM + lx);
            shortx8 v1 = *(const shortx8*)(h + (size_t)(u1 & 0x3FFFFFFF) * DIM + lx);
            shortx8 v2 = *(const shortx8*)(h + (size_t)(u2 & 0x3FFFFFFF) * DIM + lx);
            shortx8 v3 = *(const shortx8*)(h + (size_t)(u3 & 0x3FFFFFFF) * DIM + lx);
            #pragma unroll
            for (int k = 0; k < 8; ++k) {
                acc[k] += bf2f((unsigned short)v0[k]) * g0;
                acc[k] += bf2f((unsigned short)v1[k]) * g1;
                acc[k] += bf2f((unsigned short)v2[k]) * g2;
                acc[k] += bf2f((unsigned short)v3[k]) * g3;
            }
        }
        for (; j < m; ++j) {
            int u = __shfl(tag, j);
            int e = ((unsigned)u) >> 30;
            float wg = (e == 0) ? w0 : ((e == 1) ? w1 : w2);
            shortx8 v = *(const shortx8*)(h + (size_t)(u & 0x3FFFFFFF) * DIM + lx);
            #pragma unroll
            for (int k = 0; k < 8; ++k)
                acc[k] += bf2f((unsigned short)v[k]) * wg;
        }
    }
    float s1_ = 0.0f, s2_ = 0.0f;
    #pragma unroll
    for (int k = 0; k < 8; ++k) {
        float v = fmaxf(acc[k], 0.0f);
        acc[k] = v; s1_ += v; s2_ += v * v;
    }
    #pragma unroll
    for (int off = 1; off < 64; off <<= 1) {
        s1_ += __shfl_xor(s1_, off);
        s2_ += __shfl_xor(s2_, off);
    }
    float mu = s1_ * (1.0f / DIM);
    float var = s2_ * (1.0f / DIM) - mu * mu;
    float rstd = rsqrtf(var + 1e-5f);
    float4 g0 = *(const float4*)(gamma + lane * 8);
    float4 g1 = *(const float4*)(gamma + lane * 8 + 4);
    float4 b0 = *(const float4*)(beta + lane * 8);
    float4 b1 = *(const float4*)(beta + lane * 8 + 4);
    float4 o0, o1;
    o0.x = (acc[0] - mu) * rstd * g0.x + b0.x;
    o0.y = (acc[1] - mu) * rstd * g0.y + b0.y;
    o0.z = (acc[2] - mu) * rstd * g0.z + b0.z;
    o0.w = (acc[3] - mu) * rstd * g0.w + b0.w;
    o1.x = (acc[4] - mu) * rstd * g1.x + b1.x;
    o1.y = (acc[5] - mu) * rstd * g1.y + b1.y;
    o1.z = (acc[6] - mu) * rstd * g1.z + b1.z;
    o1.w = (acc[7] - mu) * rstd * g1.w + b1.w;
    float4* op = (float4*)(out + (size_t)n * DIM + lane * 8);
    op[0] = o0;
    op[1] = o1;
}

extern "C" void kernel_launch(void* const* d_in, const int* in_sizes, int n_in,
                              void* d_out, int out_size, void* d_ws, size_t ws_size,
                              hipStream_t stream) {
    const float* x     = (const float*)d_in[0];
    const float* W0    = (const float*)d_in[1];
    const float* W1    = (const float*)d_in[2];
    const float* W2    = (const float*)d_in[3];
    const float* gamma = (const float*)d_in[4];
    const float* beta  = (const float*)d_in[5];
    const int* s0  = (const int*)d_in[6];
    const int* dd0 = (const int*)d_in[7];
    const int* s1  = (const int*)d_in[8];
    const int* dd1 = (const int*)d_in[9];
    const int* s2  = (const int*)d_in[10];
    const int* dd2 = (const int*)d_in[11];
    float* out = (float*)d_out;

    // workspace layout (16B-aligned pieces)
    char* ws = (char*)d_ws;
    size_t off = 0;
    int* cnt = (int*)(ws + off);             off += 3u * N_NODES * 4u;          // 1.2 MB
    int* row_start = (int*)(ws + off);       off += (size_t)N_NODES * 4u;
    int* cursor = (int*)(ws + off);          off += (size_t)N_NODES * 4u;
    int* bsum = (int*)(ws + off);            off += 2048;
    int* src_tag = (int*)(ws + off);         off += (size_t)3 * NE * 4u;        // 2.4 MB
    unsigned short* Wc = (unsigned short*)(ws + off); off += (size_t)DIM * DIM * 2u;
    off = (off + 255) & ~255ull;
    unsigned short* h = (unsigned short*)(ws + off);                            // 102.4 MB

    hipMemsetAsync(cnt, 0, (size_t)3 * N_NODES * sizeof(int), stream);

    count_combine_kernel<<<(3 * NE + 255) / 256, 256, 0, stream>>>(
        dd0, dd1, dd2, cnt, W0, W1, W2, Wc);
    scan1_kernel<<<NSB, 512, 0, stream>>>(cnt, bsum);
    scan3_kernel<<<NSB, 512, 0, stream>>>(cnt, bsum, row_start, cursor);
    bin_kernel<<<(3 * NE + 255) / 256, 256, 0, stream>>>(
        s0, dd0, s1, dd1, s2, dd2, cursor, src_tag);

    // GEMM: h = bf16(x) @ Wc^T (bf16 out). A via LDS dbuf, B direct from L2.
    gemm_kernel<<<3128, 256, 0, stream>>>(x, Wc, h, N_NODES);

    // Fused aggregate + ReLU + LayerNorm (fp32 accumulate, full row per wave).
    gather_ln_kernel<<<(N_NODES + 3) / 4, 256, 0, stream>>>(
        h, row_start, cnt, src_tag, gamma, beta, out);
}

// Round 8
// 551.666 us; speedup vs baseline: 1.1441x; 1.1441x over previous
//
#include <hip/hip_runtime.h>
#include <hip/hip_bf16.h>
#include <cstdint>
#include <cstddef>

#define N_NODES 100000
#define DIM 512
#define NE 200000
#define NSB 196    // ceil(N_NODES/512)

typedef __attribute__((ext_vector_type(4))) float floatx4;
typedef __attribute__((ext_vector_type(8))) short shortx8;

__device__ __forceinline__ unsigned short f2bf(float f) {
    union { float f; uint32_t u; } v; v.f = f;
    uint32_t r = v.u + 0x7fff + ((v.u >> 16) & 1);   // RNE
    return (unsigned short)(r >> 16);
}

__device__ __forceinline__ float bf2f(unsigned short h) {
    union { uint32_t u; float f; } v; v.u = ((uint32_t)h) << 16;
    return v.f;
}

// 8x fp32 -> 8x bf16 (RNE) via packed v_cvt_pk_bf16_f32
__device__ __forceinline__ shortx8 cvt8(const float4 a, const float4 b) {
    union { __hip_bfloat162 h2[4]; shortx8 s8; } u;
    u.h2[0] = __float22bfloat162_rn(make_float2(a.x, a.y));
    u.h2[1] = __float22bfloat162_rn(make_float2(a.z, a.w));
    u.h2[2] = __float22bfloat162_rn(make_float2(b.x, b.y));
    u.h2[3] = __float22bfloat162_rn(make_float2(b.z, b.w));
    return u.s8;
}

__device__ __forceinline__ void load_lds16(const void* g, void* l) {
    __builtin_amdgcn_global_load_lds(
        (const __attribute__((address_space(1))) uint32_t*)g,
        (__attribute__((address_space(3))) uint32_t*)l, 16, 0, 0);
}

// ---------------- per-etype in-degree counts + Wc = (W0+W1+W2)/3 (fused, independent) ----
__global__ __launch_bounds__(256) void count_combine_kernel(
    const int* __restrict__ d0, const int* __restrict__ d1,
    const int* __restrict__ d2, int* __restrict__ cnt,
    const float* __restrict__ W0, const float* __restrict__ W1,
    const float* __restrict__ W2, unsigned short* __restrict__ Wc) {
    int t = blockIdx.x * 256 + threadIdx.x;
    if (t < DIM * DIM)
        Wc[t] = f2bf((W0[t] + W1[t] + W2[t]) * (1.0f / 3.0f));
    if (t < 3 * NE) {
        int e = t / NE;
        int i = t - e * NE;
        const int* dp = (e == 0) ? d0 : (e == 1) ? d1 : d2;
        atomicAdd(&cnt[e * N_NODES + dp[i]], 1);
    }
}

// ---------------- scan pass 1: per-block (512 rows) sums of total row length ----------------
__global__ __launch_bounds__(512) void scan1_kernel(
    const int* __restrict__ cnt, int* __restrict__ bsum) {
    int t = threadIdx.x;
    int n = blockIdx.x * 512 + t;
    int rl = 0;
    if (n < N_NODES) rl = cnt[n] + cnt[N_NODES + n] + cnt[2 * N_NODES + n];
    int v = rl;
    #pragma unroll
    for (int off = 32; off > 0; off >>= 1) v += __shfl_xor(v, off);
    __shared__ int ws_[8];
    if ((t & 63) == 0) ws_[t >> 6] = v;
    __syncthreads();
    if (t == 0) {
        int s = 0;
        #pragma unroll
        for (int i = 0; i < 8; ++i) s += ws_[i];
        bsum[blockIdx.x] = s;
    }
}

// ---------------- scan pass 2+3 fused: each block scans the 196 block sums in LDS,
// then scans its own 512 row lengths -> row_start + cursor ----------------
__global__ __launch_bounds__(512) void scan3_kernel(
    const int* __restrict__ cnt, const int* __restrict__ bsum,
    int* __restrict__ row_start, int* __restrict__ cursor) {
    __shared__ int shb[512];
    __shared__ int sh[512];
    int t = threadIdx.x;
    shb[t] = (t < NSB) ? bsum[t] : 0;
    __syncthreads();
    #pragma unroll
    for (int off = 1; off < 512; off <<= 1) {
        int add = (t >= off) ? shb[t - off] : 0;
        __syncthreads();
        shb[t] += add;
        __syncthreads();
    }
    int n = blockIdx.x * 512 + t;
    int rl = 0;
    if (n < N_NODES) rl = cnt[n] + cnt[N_NODES + n] + cnt[2 * N_NODES + n];
    sh[t] = rl;
    __syncthreads();
    #pragma unroll
    for (int off = 1; off < 512; off <<= 1) {
        int add = (t >= off) ? sh[t - off] : 0;
        __syncthreads();
        sh[t] += add;
        __syncthreads();
    }
    if (n < N_NODES) {
        int bexcl = shb[blockIdx.x] - bsum[blockIdx.x];   // exclusive block prefix
        int excl = sh[t] - rl + bexcl;
        row_start[n] = excl;
        cursor[n] = excl;
    }
}

// ---------------- bin edges into CSR: src tagged with etype in bits 30-31 ----------------
__global__ __launch_bounds__(256) void bin_kernel(
    const int* __restrict__ s0, const int* __restrict__ d0,
    const int* __restrict__ s1, const int* __restrict__ d1,
    const int* __restrict__ s2, const int* __restrict__ d2,
    int* __restrict__ cursor, int* __restrict__ src_tag) {
    int t = blockIdx.x * 256 + threadIdx.x;
    if (t >= 3 * NE) return;
    int e = t / NE;
    int i = t - e * NE;
    const int* sp; const int* dp;
    if (e == 0)      { sp = s0; dp = d0; }
    else if (e == 1) { sp = s1; dp = d1; }
    else             { sp = s2; dp = d2; }
    int d = dp[i];
    int pos = atomicAdd(&cursor[d], 1);
    src_tag[pos] = sp[i] | (e << 30);
}

// ---------------- GEMM: H = bf16(X) @ Wc^T, fused fp32->bf16 convert on A ----------------
// ROUND-4 VERBATIM (best measured: 123.6us, MfmaUtil 16.9, conflicts 0).
// 128x128 tile, BK=64 (8 K-steps), 256 threads = 2x2 waves, 4x4 16x16x32 frags/wave.
// LDS tiles row-major [128][64] bf16 with 16B-octet XOR swizzle (c ^ row&7):
// staging walks k fastest -> coalesced global; fragment ds_read_b128 conflict-free.
// A: reg-staged (cvt_pk fp32->bf16, swizzled ds_write), prefetched 1 step ahead.
// B: global_load_lds, linear dest + octet-permuted per-lane global source.
// Single-buffered 32KB LDS -> ~2-3 blocks/CU; inter-block overlap does the latency
// hiding (rounds 5-7 proved every explicit-pipeline variant that cut occupancy lost).
// XCD-bijective swizzle: 3128 = 8*391 blocks; 4 N-tile siblings share one XCD's L2.
__global__ __launch_bounds__(256) void gemm_kernel(
    const float* __restrict__ X, const unsigned short* __restrict__ B,
    unsigned short* __restrict__ H, int M) {
    __shared__ alignas(16) unsigned short As[128 * 64];   // 16 KB
    __shared__ alignas(16) unsigned short Bs[128 * 64];   // 16 KB
    const int tid = threadIdx.x;
    const int lane = tid & 63;
    const int w = tid >> 6;            // 0..3
    const int wr = w >> 1, wc = w & 1; // wave grid 2x2
    const int q = lane >> 4, r = lane & 15;

    int lid = ((int)blockIdx.x & 7) * 391 + ((int)blockIdx.x >> 3);
    int mt = lid >> 2, nt = lid & 3;
    int m0 = mt * 128, n0 = nt * 128;

    // A staging geometry: chunk ca = i*256 + tid; row = i*32 + (tid>>3), octet = tid&7
    const int arow = tid >> 3;          // 0..31
    const int ac = tid & 7;             // k-octet
    const int acs = ac ^ (arow & 7);    // swizzled octet position
    const unsigned abyte = (unsigned)arow * 128 + (unsigned)acs * 16;
    const float* aptr[4];
    #pragma unroll
    for (int i = 0; i < 4; ++i) {
        int gm = m0 + i * 32 + arow; if (gm >= M) gm = M - 1;   // clamp tail reads
        aptr[i] = X + (size_t)gm * DIM + ac * 8;
    }
    float4 areg[4][2];
    auto aload = [&](int k0_) {
        #pragma unroll
        for (int i = 0; i < 4; ++i) {
            areg[i][0] = *(const float4*)(aptr[i] + k0_);
            areg[i][1] = *(const float4*)(aptr[i] + k0_ + 4);
        }
    };

    floatx4 acc[4][4] = {};
    aload(0);

    for (int k0 = 0; k0 < DIM; k0 += 64) {
        // stage B: linear LDS dest, inverse-swizzled per-lane global source
        #pragma unroll
        for (int i = 0; i < 4; ++i) {
            int ch = i * 256 + tid;
            int row = ch >> 3, c0 = ch & 7;
            int cs = c0 ^ (row & 7);
            load_lds16(&B[(size_t)(n0 + row) * DIM + k0 + cs * 8], &Bs[ch * 8]);
        }
        // stage A: packed cvt -> swizzled ds_write_b128
        #pragma unroll
        for (int i = 0; i < 4; ++i)
            *(shortx8*)((char*)As + i * 4096 + abyte) = cvt8(areg[i][0], areg[i][1]);
        __syncthreads();
        // prefetch next K-step's A (hides under ds_read + MFMA)
        if (k0 + 64 < DIM) aload(k0 + 64);

        #pragma unroll
        for (int kk = 0; kk < 2; ++kk) {
            const int kq = kk * 4 + q;                 // k-octet 0..7
            const int sc = (kq ^ (r & 7)) * 16;        // swizzled byte-in-row
            shortx8 af[4], bfr[4];
            #pragma unroll
            for (int mi = 0; mi < 4; ++mi)
                af[mi] = *(const shortx8*)((const char*)As +
                         (wr * 64 + mi * 16 + r) * 128 + sc);
            #pragma unroll
            for (int nj = 0; nj < 4; ++nj)
                bfr[nj] = *(const shortx8*)((const char*)Bs +
                          (wc * 64 + nj * 16 + r) * 128 + sc);
            #pragma unroll
            for (int mi = 0; mi < 4; ++mi)
                #pragma unroll
                for (int nj = 0; nj < 4; ++nj)
                    acc[mi][nj] = __builtin_amdgcn_mfma_f32_16x16x32_bf16(
                        af[mi], bfr[nj], acc[mi][nj], 0, 0, 0);
        }
        __syncthreads();
    }

    // C/D layout: col = r, row = q*4 + rg within each 16x16 frag
    #pragma unroll
    for (int mi = 0; mi < 4; ++mi) {
        #pragma unroll
        for (int rg = 0; rg < 4; ++rg) {
            int gm = m0 + wr * 64 + mi * 16 + q * 4 + rg;
            if (gm < M) {
                #pragma unroll
                for (int nj = 0; nj < 4; ++nj)
                    H[(size_t)gm * DIM + n0 + wc * 64 + nj * 16 + r] =
                        f2bf(acc[mi][nj][rg]);
            }
        }
    }
}

// ---------------- fused gather + ReLU + LayerNorm ----------------
// One wave per node; wave holds the full 512-dim row (lane*8..lane*8+8) in registers.
// Cooperative tag load (64/batch) + 4-wide unrolled edge loop for memory-level parallelism.
__global__ __launch_bounds__(256) void gather_ln_kernel(
    const unsigned short* __restrict__ h, const int* __restrict__ row_start,
    const int* __restrict__ cnt, const int* __restrict__ src_tag,
    const float* __restrict__ gamma, const float* __restrict__ beta,
    float* __restrict__ out) {
    const int lane = threadIdx.x & 63;
    const int n = blockIdx.x * 4 + (threadIdx.x >> 6);
    if (n >= N_NODES) return;
    const int c0 = cnt[n], c1 = cnt[N_NODES + n], c2 = cnt[2 * N_NODES + n];
    const int len = c0 + c1 + c2;
    const float w0 = 1.0f / (3.0f * (float)max(c0, 1));
    const float w1 = 1.0f / (3.0f * (float)max(c1, 1));
    const float w2 = 1.0f / (3.0f * (float)max(c2, 1));
    const int beg = row_start[n];
    const size_t lx = (size_t)lane * 8;
    float acc[8] = {};
    for (int base = 0; base < len; base += 64) {
        int rem = len - base;
        int m = rem < 64 ? rem : 64;
        int tag = (lane < m) ? src_tag[beg + base + lane] : 0;
        int j = 0;
        for (; j + 4 <= m; j += 4) {
            int u0 = __shfl(tag, j),     u1 = __shfl(tag, j + 1);
            int u2 = __shfl(tag, j + 2), u3 = __shfl(tag, j + 3);
            int e0 = ((unsigned)u0) >> 30, e1 = ((unsigned)u1) >> 30;
            int e2 = ((unsigned)u2) >> 30, e3 = ((unsigned)u3) >> 30;
            float g0 = (e0 == 0) ? w0 : ((e0 == 1) ? w1 : w2);
            float g1 = (e1 == 0) ? w0 : ((e1 == 1) ? w1 : w2);
            float g2 = (e2 == 0) ? w0 : ((e2 == 1) ? w1 : w2);
            float g3 = (e3 == 0) ? w0 : ((e3 == 1) ? w1 : w2);
            shortx8 v0 = *(const shortx8*)(h + (size_t)(u0 & 0x3FFFFFFF) * DIM + lx);
            shortx8 v1 = *(const shortx8*)(h + (size_t)(u1 & 0x3FFFFFFF) * DIM + lx);
            shortx8 v2 = *(const shortx8*)(h + (size_t)(u2 & 0x3FFFFFFF) * DIM + lx);
            shortx8 v3 = *(const shortx8*)(h + (size_t)(u3 & 0x3FFFFFFF) * DIM + lx);
            #pragma unroll
            for (int k = 0; k < 8; ++k) {
                acc[k] += bf2f((unsigned short)v0[k]) * g0;
                acc[k] += bf2f((unsigned short)v1[k]) * g1;
                acc[k] += bf2f((unsigned short)v2[k]) * g2;
                acc[k] += bf2f((unsigned short)v3[k]) * g3;
            }
        }
        for (; j < m; ++j) {
            int u = __shfl(tag, j);
            int e = ((unsigned)u) >> 30;
            float wg = (e == 0) ? w0 : ((e == 1) ? w1 : w2);
            shortx8 v = *(const shortx8*)(h + (size_t)(u & 0x3FFFFFFF) * DIM + lx);
            #pragma unroll
            for (int k = 0; k < 8; ++k)
                acc[k] += bf2f((unsigned short)v[k]) * wg;
        }
    }
    float s1_ = 0.0f, s2_ = 0.0f;
    #pragma unroll
    for (int k = 0; k < 8; ++k) {
        float v = fmaxf(acc[k], 0.0f);
        acc[k] = v; s1_ += v; s2_ += v * v;
    }
    #pragma unroll
    for (int off = 1; off < 64; off <<= 1) {
        s1_ += __shfl_xor(s1_, off);
        s2_ += __shfl_xor(s2_, off);
    }
    float mu = s1_ * (1.0f / DIM);
    float var = s2_ * (1.0f / DIM) - mu * mu;
    float rstd = rsqrtf(var + 1e-5f);
    float4 g0 = *(const float4*)(gamma + lane * 8);
    float4 g1 = *(const float4*)(gamma + lane * 8 + 4);
    float4 b0 = *(const float4*)(beta + lane * 8);
    float4 b1 = *(const float4*)(beta + lane * 8 + 4);
    float4 o0, o1;
    o0.x = (acc[0] - mu) * rstd * g0.x + b0.x;
    o0.y = (acc[1] - mu) * rstd * g0.y + b0.y;
    o0.z = (acc[2] - mu) * rstd * g0.z + b0.z;
    o0.w = (acc[3] - mu) * rstd * g0.w + b0.w;
    o1.x = (acc[4] - mu) * rstd * g1.x + b1.x;
    o1.y = (acc[5] - mu) * rstd * g1.y + b1.y;
    o1.z = (acc[6] - mu) * rstd * g1.z + b1.z;
    o1.w = (acc[7] - mu) * rstd * g1.w + b1.w;
    float4* op = (float4*)(out + (size_t)n * DIM + lane * 8);
    op[0] = o0;
    op[1] = o1;
}

extern "C" void kernel_launch(void* const* d_in, const int* in_sizes, int n_in,
                              void* d_out, int out_size, void* d_ws, size_t ws_size,
                              hipStream_t stream) {
    const float* x     = (const float*)d_in[0];
    const float* W0    = (const float*)d_in[1];
    const float* W1    = (const float*)d_in[2];
    const float* W2    = (const float*)d_in[3];
    const float* gamma = (const float*)d_in[4];
    const float* beta  = (const float*)d_in[5];
    const int* s0  = (const int*)d_in[6];
    const int* dd0 = (const int*)d_in[7];
    const int* s1  = (const int*)d_in[8];
    const int* dd1 = (const int*)d_in[9];
    const int* s2  = (const int*)d_in[10];
    const int* dd2 = (const int*)d_in[11];
    float* out = (float*)d_out;

    // workspace layout (16B-aligned pieces)
    char* ws = (char*)d_ws;
    size_t off = 0;
    int* cnt = (int*)(ws + off);             off += 3u * N_NODES * 4u;          // 1.2 MB
    int* row_start = (int*)(ws + off);       off += (size_t)N_NODES * 4u;
    int* cursor = (int*)(ws + off);          off += (size_t)N_NODES * 4u;
    int* bsum = (int*)(ws + off);            off += 2048;
    int* src_tag = (int*)(ws + off);         off += (size_t)3 * NE * 4u;        // 2.4 MB
    unsigned short* Wc = (unsigned short*)(ws + off); off += (size_t)DIM * DIM * 2u;
    off = (off + 255) & ~255ull;
    unsigned short* h = (unsigned short*)(ws + off);                            // 102.4 MB

    hipMemsetAsync(cnt, 0, (size_t)3 * N_NODES * sizeof(int), stream);

    count_combine_kernel<<<(3 * NE + 255) / 256, 256, 0, stream>>>(
        dd0, dd1, dd2, cnt, W0, W1, W2, Wc);
    scan1_kernel<<<NSB, 512, 0, stream>>>(cnt, bsum);
    scan3_kernel<<<NSB, 512, 0, stream>>>(cnt, bsum, row_start, cursor);
    bin_kernel<<<(3 * NE + 255) / 256, 256, 0, stream>>>(
        s0, dd0, s1, dd1, s2, dd2, cursor, src_tag);

    // GEMM (round-4 verbatim): h = bf16(x) @ Wc^T (bf16 out).
    gemm_kernel<<<3128, 256, 0, stream>>>(x, Wc, h, N_NODES);

    // Fused aggregate + ReLU + LayerNorm (fp32 accumulate, full row per wave).
    gather_ln_kernel<<<(N_NODES + 3) / 4, 256, 0, stream>>>(
        h, row_start, cnt, src_tag, gamma, beta, out);
}